// Round 5
// baseline (683.882 us; speedup 1.0000x reference)
//
#include <hip/hip_runtime.h>

#define N_NODES 100000
#define N_EDGES 600000
#define DIM 128
#define NUM_RELS 8
#define NBINS (NUM_RELS * N_NODES)          // node-major: key = dst*8 + r
#define SCAN_NB ((NBINS + 1023) / 1024)     // 782
#define XBLOCKS 6250
#define TBLOCKS 576
#define HBLOCKS ((N_EDGES + 255) / 256)

#define RPB 32                               // rows per fused block
#define BPB (RPB * NUM_RELS)                 // 256 bins/block
#define FBLOCKS (N_NODES / RPB)              // 3125 (exact)
#define RSTRIDE 1060                         // f32: 8*132+4  (==1 mod 8 in 16B units)
#define CSTRIDE 132                          // f32: 128+4    (==1 mod 8 in 16B units)
#define SRC_CAP 768
#define ACC_F32 (RPB * RSTRIDE)              // 33920
#define LDS_WORDS (ACC_F32 + SRC_CAP + BPB + 8)
#define LDS_BYTES (LDS_WORDS * 4)            // 139,808 B

typedef unsigned int u32;
typedef __attribute__((ext_vector_type(8))) short bf16x8;
typedef __attribute__((ext_vector_type(4))) float f32x4;

__device__ __forceinline__ u32 pack2_bf16_rn(float lo, float hi) {
    u32 a = __float_as_uint(lo);
    u32 b = __float_as_uint(hi);
    a += 0x7fffu + ((a >> 16) & 1u);
    b += 0x7fffu + ((b >> 16) & 1u);
    return (a >> 16) | (b & 0xffff0000u);
}

// ---------------------------------------------------------------------------
// prep = convert_x | transpose_w | hist+rank
__global__ __launch_bounds__(256) void prep(
    const float* __restrict__ x, uint4* __restrict__ x_bf,
    const float* __restrict__ W, const float* __restrict__ W_root,
    unsigned short* __restrict__ Wt,
    const int* __restrict__ ei, const int* __restrict__ et,
    u32* __restrict__ hist, u32* __restrict__ rank) {
    int b = blockIdx.x, tid = threadIdx.x;
    if (b < XBLOCKS) {
        int t = b * 256 + tid;
        const float4* p = reinterpret_cast<const float4*>(x) + (size_t)t * 2;
        float4 v0 = p[0], v1 = p[1];
        uint4 o;
        o.x = pack2_bf16_rn(v0.x, v0.y);
        o.y = pack2_bf16_rn(v0.z, v0.w);
        o.z = pack2_bf16_rn(v1.x, v1.y);
        o.w = pack2_bf16_rn(v1.z, v1.w);
        x_bf[t] = o;
    } else if (b < XBLOCKS + TBLOCKS) {
        int t = (b - XBLOCKS) * 256 + tid;
        int c  = t >> 14;
        int kn = t & 16383;
        int k = kn >> 7, n = kn & 127;
        float v = (c == 0) ? W_root[kn] : W[(size_t)(c - 1) * DIM * DIM + kn];
        u32 bb = __float_as_uint(v);
        bb += 0x7fffu + ((bb >> 16) & 1u);
        Wt[(size_t)c * 16384 + n * 128 + k] = (unsigned short)(bb >> 16);
    } else {
        int e = (b - XBLOCKS - TBLOCKS) * 256 + tid;
        if (e < N_EDGES) {
            int dst = ei[N_EDGES + e];
            int r   = et[e];
            rank[e] = atomicAdd(&hist[(size_t)dst * NUM_RELS + r], 1u);
        }
    }
}

// ---------------------------------------------------------------------------
__global__ __launch_bounds__(256) void scan1(const u32* __restrict__ hist,
                                             u32* __restrict__ bsum) {
    __shared__ u32 sh[256];
    int t = threadIdx.x;
    size_t base = (size_t)blockIdx.x * 1024 + t * 4;
    u32 s = 0;
#pragma unroll
    for (int j = 0; j < 4; ++j) { size_t i = base + j; if (i < NBINS) s += hist[i]; }
    sh[t] = s; __syncthreads();
    for (int off = 128; off > 0; off >>= 1) {
        if (t < off) sh[t] += sh[t + off];
        __syncthreads();
    }
    if (t == 0) bsum[blockIdx.x] = sh[0];
}

__global__ __launch_bounds__(256) void scan2(u32* __restrict__ bsum, int nb) {
    __shared__ u32 sh[256];
    int t = threadIdx.x;
    u32 v[4]; u32 s = 0;
#pragma unroll
    for (int j = 0; j < 4; ++j) { int i = t * 4 + j; v[j] = (i < nb) ? bsum[i] : 0; s += v[j]; }
    sh[t] = s; __syncthreads();
    for (int off = 1; off < 256; off <<= 1) {
        u32 add = (t >= off) ? sh[t - off] : 0;
        __syncthreads();
        sh[t] += add;
        __syncthreads();
    }
    u32 run = (t > 0) ? sh[t - 1] : 0;
#pragma unroll
    for (int j = 0; j < 4; ++j) { int i = t * 4 + j; if (i < nb) bsum[i] = run; run += v[j]; }
}

__global__ __launch_bounds__(256) void scan3(const u32* __restrict__ hist,
                                             const u32* __restrict__ bsum,
                                             u32* __restrict__ starts) {
    __shared__ u32 sh[256];
    int t = threadIdx.x;
    size_t base = (size_t)blockIdx.x * 1024 + t * 4;
    u32 v[4]; u32 s = 0;
#pragma unroll
    for (int j = 0; j < 4; ++j) { size_t i = base + j; v[j] = (i < NBINS) ? hist[i] : 0; s += v[j]; }
    sh[t] = s; __syncthreads();
    for (int off = 1; off < 256; off <<= 1) {
        u32 add = (t >= off) ? sh[t - off] : 0;
        __syncthreads();
        sh[t] += add;
        __syncthreads();
    }
    u32 run = bsum[blockIdx.x] + ((t > 0) ? sh[t - 1] : 0);
#pragma unroll
    for (int j = 0; j < 4; ++j) {
        size_t i = base + j;
        if (i < NBINS) {
            starts[i] = run;
            if (i == NBINS - 1) starts[NBINS] = run + v[j];
            run += v[j];
        }
    }
}

// pos = starts[key] + rank[e]; payload = src | bin<<17 (bin = (dst&31)*8 + r)
__global__ __launch_bounds__(256) void reorder(const int* __restrict__ ei,
                                               const int* __restrict__ et,
                                               const u32* __restrict__ starts,
                                               const u32* __restrict__ rank,
                                               u32* __restrict__ spk) {
    int e = blockIdx.x * 256 + threadIdx.x;
    if (e >= N_EDGES) return;
    int dst = ei[N_EDGES + e];
    int r   = et[e];
    u32 bin = (u32)((dst & (RPB - 1)) * NUM_RELS + r);
    spk[starts[(size_t)dst * NUM_RELS + r] + rank[e]] = (u32)ei[e] | (bin << 17);
}

// ---------------------------------------------------------------------------
// Fused: edge-parallel LDS aggregation + 9-chunk MFMA GEMM.
// Block = 32 rows, 512 threads (8 waves). Wave w owns cols [w*16,+16), 2 M-tiles.
__global__ __launch_bounds__(512, 2) void rgcn_fused(
    const u32*  __restrict__ x32,     // x_bf rows of 64 u32
    const uint4* __restrict__ x16,    // x_bf rows of 16 uint4
    const uint4* __restrict__ Wt,     // 9 * 2048 uint4
    const u32*  __restrict__ starts,  // [NBINS+1]
    const u32*  __restrict__ spk,     // [E] sorted: src | bin<<17
    const float* __restrict__ bias,
    float* __restrict__ out) {
    extern __shared__ float smem[];
    float* ACC  = smem;                        // [32][8][128] padded (RSTRIDE/CSTRIDE)
    u32*   SRCW = (u32*)(smem + ACC_F32);
    u32*   BND  = SRCW + SRC_CAP;              // 257 boundaries

    const int tid = threadIdx.x, w = tid >> 6, lane = tid & 63;
    const int g = lane >> 4, m = lane & 15;
    const int rowbase = blockIdx.x * RPB;

    // zero ACC (float4) + stage boundaries
    float4* accq = reinterpret_cast<float4*>(ACC);
#pragma unroll
    for (int i = 0; i < 17; ++i) {
        int idx = tid + i * 512;
        if (idx < ACC_F32 / 4) accq[idx] = make_float4(0.f, 0.f, 0.f, 0.f);
    }
    if (tid <= BPB) BND[tid] = starts[(size_t)blockIdx.x * BPB + tid];
    __syncthreads();

    const u32 W0 = BND[0];
    const int wtot = (int)(BND[BPB] - W0);
    for (int i = tid; i < wtot && i < SRC_CAP; i += 512) SRCW[i] = spk[W0 + i];
    __syncthreads();

    // ---- edge-parallel aggregation: 8 waves split the block's edge range
    {
        const int q  = (wtot + 7) >> 3;
        const int lo = w * q, hi = min(lo + q, wtot);
        int i = lo;
        for (; i + 4 <= hi; i += 4) {
            u32 pk[4], vv[4];
#pragma unroll
            for (int j = 0; j < 4; ++j) pk[j] = (i + j < SRC_CAP) ? SRCW[i + j] : spk[W0 + i + j];
#pragma unroll
            for (int j = 0; j < 4; ++j) vv[j] = x32[(size_t)(pk[j] & 0x1FFFFu) * 64 + lane];
#pragma unroll
            for (int j = 0; j < 4; ++j) {
                u32 bin = pk[j] >> 17;
                float* p = &ACC[(bin >> 3) * RSTRIDE + (bin & 7) * CSTRIDE + lane * 2];
                unsafeAtomicAdd(p,     __uint_as_float(vv[j] << 16));
                unsafeAtomicAdd(p + 1, __uint_as_float(vv[j] & 0xffff0000u));
            }
        }
        for (; i < hi; ++i) {
            u32 pk = (i < SRC_CAP) ? SRCW[i] : spk[W0 + i];
            u32 vv = x32[(size_t)(pk & 0x1FFFFu) * 64 + lane];
            u32 bin = pk >> 17;
            float* p = &ACC[(bin >> 3) * RSTRIDE + (bin & 7) * CSTRIDE + lane * 2];
            unsafeAtomicAdd(p,     __uint_as_float(vv << 16));
            unsafeAtomicAdd(p + 1, __uint_as_float(vv & 0xffff0000u));
        }
    }
    __syncthreads();

    // ---- MFMA phase
    f32x4 accv[2];
    accv[0] = (f32x4)0.f; accv[1] = (f32x4)0.f;
    union { uint4 u; bf16x8 h; } cv, bb;

    // chunk 0: root transform, A straight from global
#pragma unroll
    for (int ks = 0; ks < 4; ++ks) {
        bb.u = Wt[(size_t)(w * 16 + m) * 16 + ks * 4 + g];
        bf16x8 bfr = bb.h;
#pragma unroll
        for (int mt = 0; mt < 2; ++mt) {
            cv.u = x16[(size_t)(rowbase + mt * 16 + m) * 16 + ks * 4 + g];
            accv[mt] = __builtin_amdgcn_mfma_f32_16x16x32_bf16(cv.h, bfr, accv[mt], 0, 0, 0);
        }
    }

    // chunks 1..8: scale+pack A-frags from LDS acc, MFMA vs Wt
#pragma unroll 1
    for (int r = 0; r < 8; ++r) {
        const uint4* Wc = Wt + (size_t)(r + 1) * 2048;
        bf16x8 af[2][4];
#pragma unroll
        for (int mt = 0; mt < 2; ++mt) {
            int row = mt * 16 + m;
            int bin = row * 8 + r;
            float cnt = (float)(BND[bin + 1] - BND[bin]);
            float sc = __builtin_amdgcn_rcpf(fmaxf(cnt, 1.0f));
            const float* base = &ACC[row * RSTRIDE + r * CSTRIDE];
#pragma unroll
            for (int ks = 0; ks < 4; ++ks) {
                float4 f0 = *reinterpret_cast<const float4*>(base + ks * 32 + g * 8);
                float4 f1 = *reinterpret_cast<const float4*>(base + ks * 32 + g * 8 + 4);
                uint4 pv;
                pv.x = pack2_bf16_rn(f0.x * sc, f0.y * sc);
                pv.y = pack2_bf16_rn(f0.z * sc, f0.w * sc);
                pv.z = pack2_bf16_rn(f1.x * sc, f1.y * sc);
                pv.w = pack2_bf16_rn(f1.z * sc, f1.w * sc);
                cv.u = pv; af[mt][ks] = cv.h;
            }
        }
#pragma unroll
        for (int ks = 0; ks < 4; ++ks) {
            bb.u = Wc[(size_t)(w * 16 + m) * 16 + ks * 4 + g];
            bf16x8 bfr = bb.h;
#pragma unroll
            for (int mt = 0; mt < 2; ++mt)
                accv[mt] = __builtin_amdgcn_mfma_f32_16x16x32_bf16(af[mt][ks], bfr, accv[mt], 0, 0, 0);
        }
    }

    // epilogue: +bias, f32 store. C/D: col=m(+w*16), row=g*4+j
    {
        int col = w * 16 + m;
        float bv = bias[col];
#pragma unroll
        for (int mt = 0; mt < 2; ++mt)
#pragma unroll
            for (int j = 0; j < 4; ++j) {
                int rr = rowbase + mt * 16 + g * 4 + j;
                out[(size_t)rr * DIM + col] = accv[mt][j] + bv;
            }
    }
}

// ---------------------------------------------------------------------------
extern "C" void kernel_launch(void* const* d_in, const int* in_sizes, int n_in,
                              void* d_out, int out_size, void* d_ws, size_t ws_size,
                              hipStream_t stream) {
    const float* x      = (const float*)d_in[0];
    const float* W      = (const float*)d_in[1];
    const float* W_root = (const float*)d_in[2];
    const float* bias   = (const float*)d_in[3];
    const int*   ei     = (const int*)d_in[4];   // [2][E]
    const int*   et     = (const int*)d_in[5];   // [E]
    float* out = (float*)d_out;

    char* ws = (char*)d_ws;
    uint4*          x_bf   = (uint4*)(ws);                        // 25,600,000
    unsigned short* Wt     = (unsigned short*)(ws + 25600000);    //    294,912
    u32*            starts = (u32*)(ws + 25894912);               //  3,200,016
    u32*            hist   = (u32*)(ws + 29094928);               //  3,200,000
    u32*            bsum   = (u32*)(ws + 32294928);               //      4,096
    u32*            rank   = (u32*)(ws + 32299024);               //  2,400,000
    u32*            spk    = (u32*)(ws + 34699024);               //  2,400,000
    // total 37,099,024 B

    hipMemsetAsync(hist, 0, (size_t)NBINS * 4, stream);
    prep<<<XBLOCKS + TBLOCKS + HBLOCKS, 256, 0, stream>>>(x, x_bf, W, W_root, Wt, ei, et, hist, rank);
    scan1<<<SCAN_NB, 256, 0, stream>>>(hist, bsum);
    scan2<<<1, 256, 0, stream>>>(bsum, SCAN_NB);
    scan3<<<SCAN_NB, 256, 0, stream>>>(hist, bsum, starts);
    reorder<<<HBLOCKS, 256, 0, stream>>>(ei, et, starts, rank, spk);
    rgcn_fused<<<FBLOCKS, 512, LDS_BYTES, stream>>>((const u32*)x_bf, x_bf, (const uint4*)Wt,
                                                    starts, spk, bias, out);
}

// Round 6
// 422.321 us; speedup vs baseline: 1.6193x; 1.6193x over previous
//
#include <hip/hip_runtime.h>

#define N_NODES 100000
#define N_EDGES 600000
#define DIM 128
#define NUM_RELS 8
#define NBINS (NUM_RELS * N_NODES)          // node-major: key = dst*8 + r
#define SCAN_NB ((NBINS + 1023) / 1024)     // 782
#define XBLOCKS 6250
#define TBLOCKS 576
#define HBLOCKS ((N_EDGES + 255) / 256)

typedef unsigned int u32;
typedef __attribute__((ext_vector_type(8))) short bf16x8;
typedef __attribute__((ext_vector_type(4))) float f32x4;

__device__ __forceinline__ u32 pack2_bf16_rn(float lo, float hi) {
    u32 a = __float_as_uint(lo);
    u32 b = __float_as_uint(hi);
    a += 0x7fffu + ((a >> 16) & 1u);
    b += 0x7fffu + ((b >> 16) & 1u);
    return (a >> 16) | (b & 0xffff0000u);
}

// ---------------------------------------------------------------------------
// prep = convert_x | transpose_w | hist+rank
__global__ __launch_bounds__(256) void prep(
    const float* __restrict__ x, uint4* __restrict__ x_bf,
    const float* __restrict__ W, const float* __restrict__ W_root,
    unsigned short* __restrict__ Wt,
    const int* __restrict__ ei, const int* __restrict__ et,
    u32* __restrict__ hist, u32* __restrict__ rank) {
    int b = blockIdx.x, tid = threadIdx.x;
    if (b < XBLOCKS) {
        int t = b * 256 + tid;
        const float4* p = reinterpret_cast<const float4*>(x) + (size_t)t * 2;
        float4 v0 = p[0], v1 = p[1];
        uint4 o;
        o.x = pack2_bf16_rn(v0.x, v0.y);
        o.y = pack2_bf16_rn(v0.z, v0.w);
        o.z = pack2_bf16_rn(v1.x, v1.y);
        o.w = pack2_bf16_rn(v1.z, v1.w);
        x_bf[t] = o;
    } else if (b < XBLOCKS + TBLOCKS) {
        int t = (b - XBLOCKS) * 256 + tid;
        int c  = t >> 14;
        int kn = t & 16383;
        int k = kn >> 7, n = kn & 127;
        float v = (c == 0) ? W_root[kn] : W[(size_t)(c - 1) * DIM * DIM + kn];
        u32 bb = __float_as_uint(v);
        bb += 0x7fffu + ((bb >> 16) & 1u);
        Wt[(size_t)c * 16384 + n * 128 + k] = (unsigned short)(bb >> 16);
    } else {
        int e = (b - XBLOCKS - TBLOCKS) * 256 + tid;
        if (e < N_EDGES) {
            int dst = ei[N_EDGES + e];
            int r   = et[e];
            rank[e] = atomicAdd(&hist[(size_t)dst * NUM_RELS + r], 1u);
        }
    }
}

// ---------------------------------------------------------------------------
__global__ __launch_bounds__(256) void scan1(const u32* __restrict__ hist,
                                             u32* __restrict__ bsum) {
    __shared__ u32 sh[256];
    int t = threadIdx.x;
    size_t base = (size_t)blockIdx.x * 1024 + t * 4;
    u32 s = 0;
#pragma unroll
    for (int j = 0; j < 4; ++j) { size_t i = base + j; if (i < NBINS) s += hist[i]; }
    sh[t] = s; __syncthreads();
    for (int off = 128; off > 0; off >>= 1) {
        if (t < off) sh[t] += sh[t + off];
        __syncthreads();
    }
    if (t == 0) bsum[blockIdx.x] = sh[0];
}

__global__ __launch_bounds__(256) void scan2(u32* __restrict__ bsum, int nb) {
    __shared__ u32 sh[256];
    int t = threadIdx.x;
    u32 v[4]; u32 s = 0;
#pragma unroll
    for (int j = 0; j < 4; ++j) { int i = t * 4 + j; v[j] = (i < nb) ? bsum[i] : 0; s += v[j]; }
    sh[t] = s; __syncthreads();
    for (int off = 1; off < 256; off <<= 1) {
        u32 add = (t >= off) ? sh[t - off] : 0;
        __syncthreads();
        sh[t] += add;
        __syncthreads();
    }
    u32 run = (t > 0) ? sh[t - 1] : 0;
#pragma unroll
    for (int j = 0; j < 4; ++j) { int i = t * 4 + j; if (i < nb) bsum[i] = run; run += v[j]; }
}

__global__ __launch_bounds__(256) void scan3(const u32* __restrict__ hist,
                                             const u32* __restrict__ bsum,
                                             u32* __restrict__ starts) {
    __shared__ u32 sh[256];
    int t = threadIdx.x;
    size_t base = (size_t)blockIdx.x * 1024 + t * 4;
    u32 v[4]; u32 s = 0;
#pragma unroll
    for (int j = 0; j < 4; ++j) { size_t i = base + j; v[j] = (i < NBINS) ? hist[i] : 0; s += v[j]; }
    sh[t] = s; __syncthreads();
    for (int off = 1; off < 256; off <<= 1) {
        u32 add = (t >= off) ? sh[t - off] : 0;
        __syncthreads();
        sh[t] += add;
        __syncthreads();
    }
    u32 run = bsum[blockIdx.x] + ((t > 0) ? sh[t - 1] : 0);
#pragma unroll
    for (int j = 0; j < 4; ++j) {
        size_t i = base + j;
        if (i < NBINS) {
            starts[i] = run;
            if (i == NBINS - 1) starts[NBINS] = run + v[j];
            run += v[j];
        }
    }
}

// pos = starts[key] + rank[e]; spk = src | rel<<17; wgt = 1/cnt(dst,rel)
__global__ __launch_bounds__(256) void reorder(const int* __restrict__ ei,
                                               const int* __restrict__ et,
                                               const u32* __restrict__ starts,
                                               const u32* __restrict__ hist,
                                               const u32* __restrict__ rank,
                                               u32* __restrict__ spk,
                                               float* __restrict__ wgt) {
    int e = blockIdx.x * 256 + threadIdx.x;
    if (e >= N_EDGES) return;
    int dst = ei[N_EDGES + e];
    int r   = et[e];
    size_t key = (size_t)dst * NUM_RELS + r;
    u32 pos = starts[key] + rank[e];
    spk[pos] = (u32)ei[e] | ((u32)r << 17);
    wgt[pos] = 1.0f / (float)hist[key];
}

// ---------------------------------------------------------------------------
// ymm: y[c-c0][row][:] = x_bf[row] @ Wt[c]  for c in [c0,c1), bf16 out.
// 4 waves x 16 rows; swapped-operand MFMA so lane holds 4 consecutive y-cols.
__global__ __launch_bounds__(256) void ymm(const uint4* __restrict__ x16,
                                           const uint4* __restrict__ Wt,
                                           u32* __restrict__ y,
                                           int c0, int c1) {
    const int tid = threadIdx.x, w = tid >> 6, lane = tid & 63;
    const int g = lane >> 4, m = lane & 15;
    const int row = blockIdx.x * 64 + w * 16 + m;
    const int rowc = row < N_NODES ? row : N_NODES - 1;

    union { uint4 u; bf16x8 h; } xf[4], af;
#pragma unroll
    for (int ks = 0; ks < 4; ++ks) xf[ks].u = x16[(size_t)rowc * 16 + ks * 4 + g];

#pragma unroll 1
    for (int c = c0; c < c1; ++c) {
        const uint4* Wc = Wt + (size_t)c * 2048;
        f32x4 acc[8];
#pragma unroll
        for (int cb = 0; cb < 8; ++cb) acc[cb] = (f32x4)0.0f;

#pragma unroll
        for (int ks = 0; ks < 4; ++ks) {
#pragma unroll
            for (int cb = 0; cb < 8; ++cb) {
                af.u = Wc[(size_t)(cb * 16 + m) * 16 + ks * 4 + g];
                // D'[ycol][yrow]: first operand = Wt (rows = y-cols), second = x
                acc[cb] = __builtin_amdgcn_mfma_f32_16x16x32_bf16(af.h, xf[ks].h, acc[cb], 0, 0, 0);
            }
        }

        if (row < N_NODES) {
            u32* yr = y + ((size_t)(c - c0) * N_NODES + row) * 64;
#pragma unroll
            for (int cb = 0; cb < 8; ++cb) {
                uint2 pv;
                pv.x = pack2_bf16_rn(acc[cb][0], acc[cb][1]);
                pv.y = pack2_bf16_rn(acc[cb][2], acc[cb][3]);
                *reinterpret_cast<uint2*>(yr + cb * 8 + g * 2) = pv;
            }
        }
    }
}

// ---------------------------------------------------------------------------
// gather_out: one wave per dst. out[dst] (+)= sum_e w_e * y[rel_e+1-c0][src_e]
// (+ y0[dst] + bias on the first pass). No atomics, no LDS.
__global__ __launch_bounds__(256) void gather_out(const u32* __restrict__ y,
                                                  const u32* __restrict__ spk,
                                                  const float* __restrict__ wgt,
                                                  const u32* __restrict__ starts,
                                                  const float* __restrict__ bias,
                                                  float* __restrict__ out,
                                                  int c0, int c1) {
    const int dst  = blockIdx.x * 4 + (threadIdx.x >> 6);
    const int lane = threadIdx.x & 63;
    const int a = (c0 == 0) ? 0 : c0 - 1;    // rel range [a,b) this pass
    const int b = c1 - 1;

    const u32 s = starts[(size_t)dst * 8 + a];
    const u32 e = starts[(size_t)dst * 8 + b];

    float acc0 = 0.f, acc1 = 0.f;
    const u32 dummy = (u32)a << 17;

    for (u32 i = s; i < e; i += 64) {
        int bn = (int)(e - i); if (bn > 64) bn = 64;
        u32 pk = dummy; float wv = 0.f;
        if (lane < bn) { pk = spk[i + lane]; wv = wgt[i + lane]; }
        int nb4 = (bn + 3) & ~3;
        for (int j = 0; j < nb4; j += 4) {
            u32 p0 = (u32)__shfl((int)pk, j);
            u32 p1 = (u32)__shfl((int)pk, j + 1);
            u32 p2 = (u32)__shfl((int)pk, j + 2);
            u32 p3 = (u32)__shfl((int)pk, j + 3);
            float w0 = __shfl(wv, j),     w1 = __shfl(wv, j + 1);
            float w2 = __shfl(wv, j + 2), w3 = __shfl(wv, j + 3);
            u32 v0 = y[((size_t)((p0 >> 17) + 1 - c0) * N_NODES + (p0 & 0x1FFFFu)) * 64 + lane];
            u32 v1 = y[((size_t)((p1 >> 17) + 1 - c0) * N_NODES + (p1 & 0x1FFFFu)) * 64 + lane];
            u32 v2 = y[((size_t)((p2 >> 17) + 1 - c0) * N_NODES + (p2 & 0x1FFFFu)) * 64 + lane];
            u32 v3 = y[((size_t)((p3 >> 17) + 1 - c0) * N_NODES + (p3 & 0x1FFFFu)) * 64 + lane];
            acc0 += w0 * __uint_as_float(v0 << 16);
            acc1 += w0 * __uint_as_float(v0 & 0xffff0000u);
            acc0 += w1 * __uint_as_float(v1 << 16);
            acc1 += w1 * __uint_as_float(v1 & 0xffff0000u);
            acc0 += w2 * __uint_as_float(v2 << 16);
            acc1 += w2 * __uint_as_float(v2 & 0xffff0000u);
            acc0 += w3 * __uint_as_float(v3 << 16);
            acc1 += w3 * __uint_as_float(v3 & 0xffff0000u);
        }
    }

    float2* po = reinterpret_cast<float2*>(out) + (size_t)dst * 64 + lane;
    if (c0 == 0) {
        u32 v0 = y[(size_t)dst * 64 + lane];             // chunk 0 = root transform
        float2 o;
        o.x = acc0 + __uint_as_float(v0 << 16)          + bias[lane * 2];
        o.y = acc1 + __uint_as_float(v0 & 0xffff0000u)  + bias[lane * 2 + 1];
        *po = o;
    } else {
        float2 o = *po;
        o.x += acc0; o.y += acc1;
        *po = o;
    }
}

// ---------------------------------------------------------------------------
extern "C" void kernel_launch(void* const* d_in, const int* in_sizes, int n_in,
                              void* d_out, int out_size, void* d_ws, size_t ws_size,
                              hipStream_t stream) {
    const float* x      = (const float*)d_in[0];
    const float* W      = (const float*)d_in[1];
    const float* W_root = (const float*)d_in[2];
    const float* bias   = (const float*)d_in[3];
    const int*   ei     = (const int*)d_in[4];   // [2][E]
    const int*   et     = (const int*)d_in[5];   // [E]
    float* out = (float*)d_out;

    char* ws = (char*)d_ws;
    uint4*          x_bf   = (uint4*)(ws);                        // 25,600,000
    unsigned short* Wt     = (unsigned short*)(ws + 25600000);    //    294,912
    u32*            starts = (u32*)(ws + 25894912);               //  3,200,016
    u32*            hist   = (u32*)(ws + 29094928);               //  3,200,000
    u32*            bsum   = (u32*)(ws + 32294928);               //      4,096
    u32*            rank   = (u32*)(ws + 32299024);               //  2,400,000
    u32*            spk    = (u32*)(ws + 34699024);               //  2,400,000
    float*          wgt    = (float*)(ws + 37099024);             //  2,400,000
    u32*            y      = (u32*)(ws + 39499024);               //  cmax * 25,600,000

    int cmax = 1;
    if (ws_size > 39499024u + 25600000u) {
        long long avail = (long long)ws_size - 39499024ll;
        cmax = (int)(avail / 25600000ll);
        if (cmax > 9) cmax = 9;
        if (cmax < 1) cmax = 1;
    }

    hipMemsetAsync(hist, 0, (size_t)NBINS * 4, stream);
    prep<<<XBLOCKS + TBLOCKS + HBLOCKS, 256, 0, stream>>>(x, x_bf, W, W_root, Wt, ei, et, hist, rank);
    scan1<<<SCAN_NB, 256, 0, stream>>>(hist, bsum);
    scan2<<<1, 256, 0, stream>>>(bsum, SCAN_NB);
    scan3<<<SCAN_NB, 256, 0, stream>>>(hist, bsum, starts);
    reorder<<<HBLOCKS, 256, 0, stream>>>(ei, et, starts, hist, rank, spk, wgt);

    for (int c0 = 0; c0 < 9; c0 += cmax) {
        int c1 = c0 + cmax < 9 ? c0 + cmax : 9;
        ymm<<<(N_NODES + 63) / 64, 256, 0, stream>>>(x_bf, (const uint4*)Wt, y, c0, c1);
        gather_out<<<N_NODES / 4, 256, 0, stream>>>(y, spk, wgt, starts, bias, out, c0, c1);
    }
}

// Round 7
// 230.255 us; speedup vs baseline: 2.9701x; 1.8341x over previous
//
#include <hip/hip_runtime.h>

#define N_NODES 100000
#define N_EDGES 600000
#define DIM 128
#define NUM_RELS 8
#define NBINS (NUM_RELS * N_NODES)          // node-major: key = dst*8 + r
#define SCAN_NB ((NBINS + 1023) / 1024)     // 782
#define XBLOCKS 6250
#define TBLOCKS 576
#define HBLOCKS ((N_EDGES + 255) / 256)

typedef unsigned int u32;
typedef __attribute__((ext_vector_type(8))) short bf16x8;
typedef __attribute__((ext_vector_type(4))) float f32x4;

__device__ __forceinline__ u32 pack2_bf16_rn(float lo, float hi) {
    u32 a = __float_as_uint(lo);
    u32 b = __float_as_uint(hi);
    a += 0x7fffu + ((a >> 16) & 1u);
    b += 0x7fffu + ((b >> 16) & 1u);
    return (a >> 16) | (b & 0xffff0000u);
}

// ---------------------------------------------------------------------------
// prep = convert_x | transpose_w | hist+rank
__global__ __launch_bounds__(256) void prep(
    const float* __restrict__ x, uint4* __restrict__ x_bf,
    const float* __restrict__ W, const float* __restrict__ W_root,
    unsigned short* __restrict__ Wt,
    const int* __restrict__ ei, const int* __restrict__ et,
    u32* __restrict__ hist, u32* __restrict__ rank) {
    int b = blockIdx.x, tid = threadIdx.x;
    if (b < XBLOCKS) {
        int t = b * 256 + tid;
        const float4* p = reinterpret_cast<const float4*>(x) + (size_t)t * 2;
        float4 v0 = p[0], v1 = p[1];
        uint4 o;
        o.x = pack2_bf16_rn(v0.x, v0.y);
        o.y = pack2_bf16_rn(v0.z, v0.w);
        o.z = pack2_bf16_rn(v1.x, v1.y);
        o.w = pack2_bf16_rn(v1.z, v1.w);
        x_bf[t] = o;
    } else if (b < XBLOCKS + TBLOCKS) {
        int t = (b - XBLOCKS) * 256 + tid;
        int c  = t >> 14;
        int kn = t & 16383;
        int k = kn >> 7, n = kn & 127;
        float v = (c == 0) ? W_root[kn] : W[(size_t)(c - 1) * DIM * DIM + kn];
        u32 bb = __float_as_uint(v);
        bb += 0x7fffu + ((bb >> 16) & 1u);
        Wt[(size_t)c * 16384 + n * 128 + k] = (unsigned short)(bb >> 16);
    } else {
        int e = (b - XBLOCKS - TBLOCKS) * 256 + tid;
        if (e < N_EDGES) {
            int dst = ei[N_EDGES + e];
            int r   = et[e];
            rank[e] = atomicAdd(&hist[(size_t)dst * NUM_RELS + r], 1u);
        }
    }
}

// ---------------------------------------------------------------------------
__global__ __launch_bounds__(256) void scan1(const u32* __restrict__ hist,
                                             u32* __restrict__ bsum) {
    __shared__ u32 sh[256];
    int t = threadIdx.x;
    size_t base = (size_t)blockIdx.x * 1024 + t * 4;
    u32 s = 0;
#pragma unroll
    for (int j = 0; j < 4; ++j) { size_t i = base + j; if (i < NBINS) s += hist[i]; }
    sh[t] = s; __syncthreads();
    for (int off = 128; off > 0; off >>= 1) {
        if (t < off) sh[t] += sh[t + off];
        __syncthreads();
    }
    if (t == 0) bsum[blockIdx.x] = sh[0];
}

__global__ __launch_bounds__(256) void scan2(u32* __restrict__ bsum, int nb) {
    __shared__ u32 sh[256];
    int t = threadIdx.x;
    u32 v[4]; u32 s = 0;
#pragma unroll
    for (int j = 0; j < 4; ++j) { int i = t * 4 + j; v[j] = (i < nb) ? bsum[i] : 0; s += v[j]; }
    sh[t] = s; __syncthreads();
    for (int off = 1; off < 256; off <<= 1) {
        u32 add = (t >= off) ? sh[t - off] : 0;
        __syncthreads();
        sh[t] += add;
        __syncthreads();
    }
    u32 run = (t > 0) ? sh[t - 1] : 0;
#pragma unroll
    for (int j = 0; j < 4; ++j) { int i = t * 4 + j; if (i < nb) bsum[i] = run; run += v[j]; }
}

__global__ __launch_bounds__(256) void scan3(const u32* __restrict__ hist,
                                             const u32* __restrict__ bsum,
                                             u32* __restrict__ starts) {
    __shared__ u32 sh[256];
    int t = threadIdx.x;
    size_t base = (size_t)blockIdx.x * 1024 + t * 4;
    u32 v[4]; u32 s = 0;
#pragma unroll
    for (int j = 0; j < 4; ++j) { size_t i = base + j; v[j] = (i < NBINS) ? hist[i] : 0; s += v[j]; }
    sh[t] = s; __syncthreads();
    for (int off = 1; off < 256; off <<= 1) {
        u32 add = (t >= off) ? sh[t - off] : 0;
        __syncthreads();
        sh[t] += add;
        __syncthreads();
    }
    u32 run = bsum[blockIdx.x] + ((t > 0) ? sh[t - 1] : 0);
#pragma unroll
    for (int j = 0; j < 4; ++j) {
        size_t i = base + j;
        if (i < NBINS) {
            starts[i] = run;
            if (i == NBINS - 1) starts[NBINS] = run + v[j];
            run += v[j];
        }
    }
}

// pos = starts[key] + rank[e]; spk = src | local_bin<<17, local_bin=(dst&31)*8+r
__global__ __launch_bounds__(256) void reorder(const int* __restrict__ ei,
                                               const int* __restrict__ et,
                                               const u32* __restrict__ starts,
                                               const u32* __restrict__ rank,
                                               u32* __restrict__ spk) {
    int e = blockIdx.x * 256 + threadIdx.x;
    if (e >= N_EDGES) return;
    int dst = ei[N_EDGES + e];
    int r   = et[e];
    u32 bin = (u32)((dst & 31) * NUM_RELS + r);
    spk[starts[(size_t)dst * NUM_RELS + r] + rank[e]] = (u32)ei[e] | (bin << 17);
}

// ---------------------------------------------------------------------------
// write mean row (bf16-packed, granule-XOR-swizzled) for the finished bin
#define FLUSH2() do { \
    float sc_ = __builtin_amdgcn_rcpf((float)rcnt); \
    ACC[(u32)cur_bin * 64u + ((((lane >> 2) ^ (((u32)cur_bin >> 3) & 15u)) << 2) | (u32)(lane & 3))] = \
        pack2_bf16_rn(a0 * sc_, a1 * sc_); \
} while (0)

// Fused RGCN: sorted-run register aggregation into 64KB LDS + 9-chunk MFMA.
// Block = 32 dsts (grid 3125 exact), 512 thr (8 waves). No global intermediates.
__global__ __launch_bounds__(512, 4) void rgcn_fused(
    const u32*  __restrict__ x32,     // x_bf rows of 64 u32
    const uint4* __restrict__ x16,    // x_bf rows of 16 uint4
    const uint4* __restrict__ Wt,     // 9 * 2048 uint4 (col-major granules)
    const u32*  __restrict__ starts,  // [NBINS+1]
    const u32*  __restrict__ spk,     // [E] sorted: src | local_bin<<17
    const float* __restrict__ bias,
    float* __restrict__ out) {
    extern __shared__ u32 ACC[];      // [256 bins][64 u32] bf16 means, 64 KB
    const int tid = threadIdx.x, w = tid >> 6, lane = tid & 63;
    const int g = lane >> 4, m = lane & 15;
    const int rowbase = blockIdx.x * 32;

    // zero ACC
    uint4* az = reinterpret_cast<uint4*>(ACC);
#pragma unroll
    for (int i = 0; i < 8; ++i) az[tid + i * 512] = make_uint4(0u, 0u, 0u, 0u);
    __syncthreads();

    // ---- phase 1: aggregation. wave w owns local bins [w*32, w*32+32) (4 dsts)
    {
        const u32 elo = starts[(size_t)blockIdx.x * 256 + w * 32];
        const u32 ehi = starts[(size_t)blockIdx.x * 256 + w * 32 + 32];
        int cur_bin = -1, rcnt = 0;
        float a0 = 0.f, a1 = 0.f;
        for (u32 base = elo; base < ehi; base += 64) {
            const int bn = min(64, (int)(ehi - base));
            u32 pk = 0;
            if (lane < bn) pk = spk[base + lane];
            for (int j0 = 0; j0 < bn; j0 += 8) {
                const int lim = bn - j0;
                u32 v[8];
#pragma unroll
                for (int q = 0; q < 8; ++q) {        // 8 independent row-gathers in flight
                    u32 p = (u32)__shfl((int)pk, j0 + (q < lim ? q : 0));
                    v[q] = x32[(size_t)(p & 0x1FFFFu) * 64 + lane];
                }
#pragma unroll
                for (int q = 0; q < 8; ++q) {        // static index only (no scratch)
                    if (q < lim) {
                        const u32 p = (u32)__shfl((int)pk, j0 + q);
                        const int b = (int)(p >> 17);
                        if (b != cur_bin) {          // wave-uniform
                            if (rcnt > 0) FLUSH2();
                            cur_bin = b; a0 = 0.f; a1 = 0.f; rcnt = 0;
                        }
                        const u32 vv = v[q];
                        a0 += __uint_as_float(vv << 16);
                        a1 += __uint_as_float(vv & 0xffff0000u);
                        ++rcnt;
                    }
                }
            }
        }
        if (rcnt > 0) FLUSH2();
    }
    __syncthreads();

    // ---- phase 2: 9-chunk MFMA. wave w owns out-cols [w*16, w*16+16), 2 M-tiles.
    const uint4* ATq = reinterpret_cast<const uint4*>(ACC);
    f32x4 accv[2];
    accv[0] = (f32x4)0.f; accv[1] = (f32x4)0.f;
    union { uint4 u; bf16x8 h; } av, bv;
    const int colg = w * 16 + m;

    // chunk 0: root transform, A straight from global
#pragma unroll
    for (int ks = 0; ks < 4; ++ks) {
        bv.u = Wt[(size_t)colg * 16 + ks * 4 + g];
        bf16x8 bf = bv.h;
#pragma unroll
        for (int mt = 0; mt < 2; ++mt) {
            av.u = x16[(size_t)(rowbase + mt * 16 + m) * 16 + ks * 4 + g];
            accv[mt] = __builtin_amdgcn_mfma_f32_16x16x32_bf16(av.h, bf, accv[mt], 0, 0, 0);
        }
    }

    // chunks 1..8: A from swizzled LDS means
#pragma unroll 1
    for (int r = 0; r < 8; ++r) {
        const uint4* Wc = Wt + (size_t)(r + 1) * 2048;
#pragma unroll
        for (int ks = 0; ks < 4; ++ks) {
            bv.u = Wc[(size_t)colg * 16 + ks * 4 + g];
            bf16x8 bf = bv.h;
#pragma unroll
            for (int mt = 0; mt < 2; ++mt) {
                av.u = ATq[(size_t)((mt * 16 + m) * 8 + r) * 16 + (u32)((ks * 4 + g) ^ m)];
                accv[mt] = __builtin_amdgcn_mfma_f32_16x16x32_bf16(av.h, bf, accv[mt], 0, 0, 0);
            }
        }
    }

    // epilogue: +bias, f32 store. C/D: col=m (B-col), row=g*4+j (A-row)
    {
        const float bb = bias[colg];
#pragma unroll
        for (int mt = 0; mt < 2; ++mt)
#pragma unroll
            for (int j = 0; j < 4; ++j)
                out[(size_t)(rowbase + mt * 16 + g * 4 + j) * DIM + colg] = accv[mt][j] + bb;
    }
}

// ---------------------------------------------------------------------------
extern "C" void kernel_launch(void* const* d_in, const int* in_sizes, int n_in,
                              void* d_out, int out_size, void* d_ws, size_t ws_size,
                              hipStream_t stream) {
    const float* x      = (const float*)d_in[0];
    const float* W      = (const float*)d_in[1];
    const float* W_root = (const float*)d_in[2];
    const float* bias   = (const float*)d_in[3];
    const int*   ei     = (const int*)d_in[4];   // [2][E]
    const int*   et     = (const int*)d_in[5];   // [E]
    float* out = (float*)d_out;

    char* ws = (char*)d_ws;
    uint4*          x_bf   = (uint4*)(ws);                        // 25,600,000
    unsigned short* Wt     = (unsigned short*)(ws + 25600000);    //    294,912
    u32*            starts = (u32*)(ws + 25894912);               //  3,200,016
    u32*            hist   = (u32*)(ws + 29094928);               //  3,200,000
    u32*            bsum   = (u32*)(ws + 32294928);               //      4,096
    u32*            rank   = (u32*)(ws + 32299024);               //  2,400,000
    u32*            spk    = (u32*)(ws + 34699024);               //  2,400,000
    // total 37,099,024 B

    hipMemsetAsync(hist, 0, (size_t)NBINS * 4, stream);
    prep<<<XBLOCKS + TBLOCKS + HBLOCKS, 256, 0, stream>>>(x, x_bf, W, W_root, Wt, ei, et, hist, rank);
    scan1<<<SCAN_NB, 256, 0, stream>>>(hist, bsum);
    scan2<<<1, 256, 0, stream>>>(bsum, SCAN_NB);
    scan3<<<SCAN_NB, 256, 0, stream>>>(hist, bsum, starts);
    reorder<<<HBLOCKS, 256, 0, stream>>>(ei, et, starts, rank, spk);
    rgcn_fused<<<N_NODES / 32, 512, 65536, stream>>>((const u32*)x_bf, x_bf, (const uint4*)Wt,
                                                     starts, spk, bias, out);
}